// Round 8
// baseline (126.734 us; speedup 1.0000x reference)
//
#include <hip/hip_runtime.h>

// ParallelLinear: out[b,t,o] = sum_i x[b,t,i] * W[t,o,i] + bias[t,o]
// B=512, T=1024, ISIZE=OSIZE=64, fp32 in/out.
//
// v8: the multi-t granule fix with R7's confounds removed.
//  - Block = 4 consecutive t's x 32 rows -> x reads are 1KB contiguous per
//    b-row (4x fewer DRAM page activates than the 256B-island pattern that
//    pins R0/R2/R6 at ~86us / 3.1 TB/s = half of streaming BW).
//  - 32KB LDS (X hi/lo planes only) -> 4 blocks/CU (R7 died at 2).
//  - W[t] in per-wave registers as MFMA B-frags (R7-verified layout);
//    re-read by the 16 chunk-blocks of a quad, which are launch-adjacent
//    -> L2-hot.
//  - Epilogue: direct global stores (R6-verified mapping), no LDS roundtrip
//    (R7's 2.1M-conflict bug eliminated).
//  - Numerics: R6/R7-verified 3-term bf16 hi/lo split (absmax 0.0156 passes).

#define T_DIM 1024
#define B_DIM 512
#define KSZ 64
#define OSZ 64
#define ROWS 32
#define NT 4
#define NCHUNK (B_DIM / ROWS)    // 16

typedef __attribute__((ext_vector_type(8))) short   short8;   // 8 bf16
typedef __attribute__((ext_vector_type(4))) float   f32x4;

static __device__ __forceinline__ unsigned short f2bf(float f) {
    unsigned u = __float_as_uint(f);
    u += 0x7FFFu + ((u >> 16) & 1u);          // RNE
    return (unsigned short)(u >> 16);
}
static __device__ __forceinline__ float bf2f(unsigned short h) {
    return __uint_as_float((unsigned)h << 16);
}

__global__ __launch_bounds__(256, 4) void pl_kernel(
    const float* __restrict__ x,
    const float* __restrict__ W,
    const float* __restrict__ bias,
    float* __restrict__ out)
{
    // planes: [sq=t-slot][32 rows][64 k] bf16, 16B-granule XOR swizzle
    __shared__ unsigned short Xh[NT * ROWS * KSZ];   // 16 KB
    __shared__ unsigned short Xl[NT * ROWS * KSZ];   // 16 KB

    const int quad  = blockIdx.x >> 4;     // 0..255
    const int chunk = blockIdx.x & 15;     // 0..15  (quad-major: W stays L2-hot)
    const int T0    = quad * NT;
    const int row0  = chunk * ROWS;
    const int tid   = threadIdx.x;
    const int w     = tid >> 6;            // wave id = t-slot
    const int l     = tid & 63;
    const int n     = l & 15;              // o-low / frag col
    const int kq    = l >> 4;              // 0..3

    // ===== W gather: wave w -> registers (B-frags), R7-verified layout =====
    // lane holds W[o = 16ct + n][k = (ks*4+kq)*8 + j]
    short8 wh[4][2], wl[4][2];
    {
        const float* wp = W + ((size_t)(T0 + w) * OSZ + n) * KSZ + kq * 8;
        #pragma unroll
        for (int ct = 0; ct < 4; ++ct) {
            #pragma unroll
            for (int ks = 0; ks < 2; ++ks) {
                const float* p = wp + (size_t)ct * 16 * KSZ + ks * 32;
                float4 f0 = *(const float4*)(p);
                float4 f1 = *(const float4*)(p + 4);
                float a[8] = {f0.x, f0.y, f0.z, f0.w, f1.x, f1.y, f1.z, f1.w};
                short8 h, lo;
                #pragma unroll
                for (int j = 0; j < 8; ++j) {
                    unsigned short hh = f2bf(a[j]);
                    h[j]  = (short)hh;
                    lo[j] = (short)f2bf(a[j] - bf2f(hh));
                }
                wh[ct][ks] = h; wl[ct][ks] = lo;
            }
        }
    }

    // ===== X staging: 1KB-contiguous global reads -> swizzled planes =====
    // thread (sr=tid>>3, sq=(tid>>1)&3, half=tid&1) loads
    // x[row0+sr][T0+sq][32*half .. 32*half+31]  (128B; 8 threads = 1KB run)
    {
        const int sr   = tid >> 3;
        const int sq   = (tid >> 1) & 3;
        const int half = tid & 1;
        const float* xp = x + ((size_t)(row0 + sr) * T_DIM + (T0 + sq)) * KSZ + 32 * half;
        unsigned short* xh = Xh + sq * (ROWS * KSZ) + sr * KSZ;
        unsigned short* xl = Xl + sq * (ROWS * KSZ) + sr * KSZ;
        const int swz = (sr & 7) ^ ((sq & 1) << 2);
        #pragma unroll
        for (int bb = 0; bb < 4; ++bb) {             // granule bb of this half
            float4 f0 = *(const float4*)(xp + bb * 8);
            float4 f1 = *(const float4*)(xp + bb * 8 + 4);
            float a[8] = {f0.x, f0.y, f0.z, f0.w, f1.x, f1.y, f1.z, f1.w};
            short8 h, lo;
            #pragma unroll
            for (int j = 0; j < 8; ++j) {
                unsigned short hh = f2bf(a[j]);
                h[j]  = (short)hh;
                lo[j] = (short)f2bf(a[j] - bf2f(hh));
            }
            const int g = (half * 4 + bb) ^ swz;     // stored granule position
            *(short8*)(xh + g * 8) = h;
            *(short8*)(xl + g * 8) = lo;
        }
    }

    __syncthreads();

    // ===== A-frags from own plane (sq = w): lane holds A[m-row=n][k=kq*8+j] =====
    short8 ah[2][2], al[2][2];
    #pragma unroll
    for (int m = 0; m < 2; ++m) {
        const int arow = 16 * m + n;
        const unsigned short* ph = Xh + w * (ROWS * KSZ) + arow * KSZ;
        const unsigned short* pl = Xl + w * (ROWS * KSZ) + arow * KSZ;
        const int s2 = (arow & 7) ^ ((w & 1) << 2);
        #pragma unroll
        for (int ks = 0; ks < 2; ++ks) {
            const int g = (ks * 4 + kq) ^ s2;
            ah[m][ks] = *(const short8*)(ph + g * 8);
            al[m][ks] = *(const short8*)(pl + g * 8);
        }
    }

    // ===== MFMA: 2m x 4ct x 2ks x 3 terms = 48 per wave =====
    f32x4 acc[2][4] = {};
    #pragma unroll
    for (int m = 0; m < 2; ++m) {
        #pragma unroll
        for (int ct = 0; ct < 4; ++ct) {
            #pragma unroll
            for (int ks = 0; ks < 2; ++ks) {
                acc[m][ct] = __builtin_amdgcn_mfma_f32_16x16x32_bf16(ah[m][ks], wh[ct][ks], acc[m][ct], 0, 0, 0);
                acc[m][ct] = __builtin_amdgcn_mfma_f32_16x16x32_bf16(al[m][ks], wh[ct][ks], acc[m][ct], 0, 0, 0);
                acc[m][ct] = __builtin_amdgcn_mfma_f32_16x16x32_bf16(ah[m][ks], wl[ct][ks], acc[m][ct], 0, 0, 0);
            }
        }
    }

    // ===== epilogue: direct stores (C/D map: col = n, row = 4*kq + j) =====
    const int t = T0 + w;
    #pragma unroll
    for (int ct = 0; ct < 4; ++ct) {
        const float bv = bias[(size_t)t * OSZ + 16 * ct + n];
        #pragma unroll
        for (int m = 0; m < 2; ++m) {
            #pragma unroll
            for (int j = 0; j < 4; ++j) {
                const size_t b = (size_t)row0 + 16 * m + 4 * kq + j;
                out[(b * T_DIM + t) * OSZ + 16 * ct + n] = acc[m][ct][j] + bv;
            }
        }
    }
}

extern "C" void kernel_launch(void* const* d_in, const int* in_sizes, int n_in,
                              void* d_out, int out_size, void* d_ws, size_t ws_size,
                              hipStream_t stream) {
    const float* x    = (const float*)d_in[0];
    const float* W    = (const float*)d_in[1];
    const float* bias = (const float*)d_in[2];
    float* out        = (float*)d_out;

    dim3 grid((T_DIM / NT) * NCHUNK);    // 256 * 16 = 4096 blocks
    dim3 block(256);
    pl_kernel<<<grid, block, 0, stream>>>(x, W, bias, out);
}

// Round 9
// 88.272 us; speedup vs baseline: 1.4357x; 1.4357x over previous
//
#include <hip/hip_runtime.h>

// ParallelLinear: out[b,t,o] = sum_i x[b,t,i] * W[t,o,i] + bias[t,o]
// B=512, T=1024, ISIZE=OSIZE=64, fp32 in/out.
//
// v9: clean 1KB-granule experiment (R8's spill artifact removed).
// R8 failed because __launch_bounds__(256,4) capped VGPR at 128 while the
// 4-waves-own-full-t structure needs ~130 -> scratch spill (+120MB TCC
// traffic, VGPR_Count=64 tell). v9 splits each t across TWO waves
// (8 waves: ws = t-slot, wo = o-half) so per-wave demand is ~100 VGPR:
//   W-frags 2ct*2ks*(hi,lo) = 8 short8 = 32, acc 2m*2ct = 16, A-frags 32.
// Block = 4 consecutive t's x 32 rows: x reads and out writes are 1KB
// contiguous per b-row (vs 256B islands that pin R0/R2/R6 at 3.1 TB/s,
// consistent with a DRAM activate-rate cap of ~4act/tFAW * 256B).
// X planes 32KB LDS -> 2 blocks/CU = 16 waves/CU (R6 capacity).
// All LDS accesses <=2-way at 16-lane phase granularity (free, m136).
// Numerics: R6/R7/R8-verified 3-term bf16 hi/lo split (absmax 0.0156).

#define T_DIM 1024
#define B_DIM 512
#define KSZ 64
#define OSZ 64
#define ROWS 32
#define NT 4
#define NCHUNK (B_DIM / ROWS)    // 16

typedef __attribute__((ext_vector_type(8))) short   short8;   // 8 bf16
typedef __attribute__((ext_vector_type(4))) float   f32x4;

static __device__ __forceinline__ unsigned short f2bf(float f) {
    unsigned u = __float_as_uint(f);
    u += 0x7FFFu + ((u >> 16) & 1u);          // RNE
    return (unsigned short)(u >> 16);
}
static __device__ __forceinline__ float bf2f(unsigned short h) {
    return __uint_as_float((unsigned)h << 16);
}

__global__ __launch_bounds__(512, 4) void pl_kernel(
    const float* __restrict__ x,
    const float* __restrict__ W,
    const float* __restrict__ bias,
    float* __restrict__ out)
{
    // X planes: [sq = t-slot][32 rows][8 granules of 8 bf16], XOR-swizzled
    __shared__ unsigned short Xh[NT * ROWS * KSZ];   // 16 KB
    __shared__ unsigned short Xl[NT * ROWS * KSZ];   // 16 KB

    const int quad  = blockIdx.x >> 4;     // 0..255
    const int chunk = blockIdx.x & 15;     // 0..15 (quad-major: W stays L2-hot)
    const int T0    = quad * NT;
    const int row0  = chunk * ROWS;
    const int tid   = threadIdx.x;
    const int wid   = tid >> 6;            // 0..7
    const int ws    = wid & 3;             // t-slot
    const int wo    = wid >> 2;            // o-half
    const int l     = tid & 63;
    const int n     = l & 15;
    const int kq    = l >> 4;              // 0..3

    // ===== W gather: wave (ws,wo) -> B-frags for ct = 2wo..2wo+1 =====
    // lane holds W[o = 16ct + n][k = (ks*4+kq)*8 + j]  (R6-verified layout)
    short8 wh[2][2], wl[2][2];
    {
        #pragma unroll
        for (int co = 0; co < 2; ++co) {
            const int ct = 2 * wo + co;
            #pragma unroll
            for (int ks = 0; ks < 2; ++ks) {
                const float* p = W + (((size_t)(T0 + ws) * OSZ + 16 * ct + n) * KSZ)
                                   + ks * 32 + kq * 8;
                float4 f0 = *(const float4*)(p);
                float4 f1 = *(const float4*)(p + 4);
                float a[8] = {f0.x, f0.y, f0.z, f0.w, f1.x, f1.y, f1.z, f1.w};
                short8 h, lo;
                #pragma unroll
                for (int j = 0; j < 8; ++j) {
                    unsigned short hh = f2bf(a[j]);
                    h[j]  = (short)hh;
                    lo[j] = (short)f2bf(a[j] - bf2f(hh));
                }
                wh[co][ks] = h; wl[co][ks] = lo;
            }
        }
    }

    // ===== X staging: 1KB-contiguous reads (16 lanes cover x[b][T0..T0+3][:]) =====
    // thread: sr = tid>>4 (row), sq = (tid>>2)&3 (t-slot), kc = tid&3 (16-float chunk)
    {
        const int sr = tid >> 4;
        const int sq = (tid >> 2) & 3;
        const int kc = tid & 3;
        const float* xp = x + ((size_t)(row0 + sr) * T_DIM + (T0 + sq)) * KSZ + kc * 16;
        float4 f0 = *(const float4*)(xp);
        float4 f1 = *(const float4*)(xp + 4);
        float4 f2 = *(const float4*)(xp + 8);
        float4 f3 = *(const float4*)(xp + 12);
        float a[8]  = {f0.x, f0.y, f0.z, f0.w, f1.x, f1.y, f1.z, f1.w};
        float b2[8] = {f2.x, f2.y, f2.z, f2.w, f3.x, f3.y, f3.z, f3.w};
        short8 h0, l0, h1, l1;
        #pragma unroll
        for (int j = 0; j < 8; ++j) {
            unsigned short hh = f2bf(a[j]);
            h0[j] = (short)hh; l0[j] = (short)f2bf(a[j] - bf2f(hh));
            unsigned short h2 = f2bf(b2[j]);
            h1[j] = (short)h2; l1[j] = (short)f2bf(b2[j] - bf2f(h2));
        }
        unsigned short* xh = Xh + sq * (ROWS * KSZ) + sr * KSZ;
        unsigned short* xl = Xl + sq * (ROWS * KSZ) + sr * KSZ;
        // granule kb stored at kb ^ (sr&7) ^ sq: writes <=2-way per 16-lane phase
        const int swz = (sr & 7) ^ sq;
        const int g0  = (2 * kc)     ^ swz;
        const int g1  = (2 * kc + 1) ^ swz;
        *(short8*)(xh + g0 * 8) = h0;
        *(short8*)(xl + g0 * 8) = l0;
        *(short8*)(xh + g1 * 8) = h1;
        *(short8*)(xl + g1 * 8) = l1;
    }

    __syncthreads();

    // ===== A-frags from plane ws: lane holds A[row = 16m+n][k = (ks*4+kq)*8+j] =====
    short8 ah[2][2], al[2][2];
    #pragma unroll
    for (int m = 0; m < 2; ++m) {
        const int arow = 16 * m + n;
        const unsigned short* ph = Xh + ws * (ROWS * KSZ) + arow * KSZ;
        const unsigned short* pl = Xl + ws * (ROWS * KSZ) + arow * KSZ;
        const int s2 = (arow & 7) ^ ws;
        #pragma unroll
        for (int ks = 0; ks < 2; ++ks) {
            const int g = (ks * 4 + kq) ^ s2;
            ah[m][ks] = *(const short8*)(ph + g * 8);
            al[m][ks] = *(const short8*)(pl + g * 8);
        }
    }

    // ===== MFMA: 2m x 2co x 2ks x 3 terms = 24 per wave =====
    f32x4 acc[2][2] = {};
    #pragma unroll
    for (int m = 0; m < 2; ++m) {
        #pragma unroll
        for (int co = 0; co < 2; ++co) {
            #pragma unroll
            for (int ks = 0; ks < 2; ++ks) {
                acc[m][co] = __builtin_amdgcn_mfma_f32_16x16x32_bf16(ah[m][ks], wh[co][ks], acc[m][co], 0, 0, 0);
                acc[m][co] = __builtin_amdgcn_mfma_f32_16x16x32_bf16(al[m][ks], wh[co][ks], acc[m][co], 0, 0, 0);
                acc[m][co] = __builtin_amdgcn_mfma_f32_16x16x32_bf16(ah[m][ks], wl[co][ks], acc[m][co], 0, 0, 0);
            }
        }
    }

    // ===== epilogue: direct stores (C/D map: col = n, row = 4*kq + j) =====
    const int t = T0 + ws;
    #pragma unroll
    for (int co = 0; co < 2; ++co) {
        const int ct = 2 * wo + co;
        const float bv = bias[(size_t)t * OSZ + 16 * ct + n];
        #pragma unroll
        for (int m = 0; m < 2; ++m) {
            #pragma unroll
            for (int j = 0; j < 4; ++j) {
                const size_t b = (size_t)row0 + 16 * m + 4 * kq + j;
                out[(b * T_DIM + t) * OSZ + 16 * ct + n] = acc[m][co][j] + bv;
            }
        }
    }
}

extern "C" void kernel_launch(void* const* d_in, const int* in_sizes, int n_in,
                              void* d_out, int out_size, void* d_ws, size_t ws_size,
                              hipStream_t stream) {
    const float* x    = (const float*)d_in[0];
    const float* W    = (const float*)d_in[1];
    const float* bias = (const float*)d_in[2];
    float* out        = (float*)d_out;

    dim3 grid((T_DIM / NT) * NCHUNK);    // 256 * 16 = 4096 blocks
    dim3 block(512);
    pl_kernel<<<grid, block, 0, stream>>>(x, W, bias, out);
}